// Round 7
// baseline (1185.884 us; speedup 1.0000x reference)
//
#include <hip/hip_runtime.h>

#define R_ET 8
#define DH 128

typedef __bf16 bf16x8 __attribute__((ext_vector_type(8)));
typedef float f32x4 __attribute__((ext_vector_type(4)));
typedef ushort u16x8 __attribute__((ext_vector_type(8)));

__device__ __forceinline__ ushort f2bf(float f) {
  unsigned u = __float_as_uint(f);
  u += 0x7fff + ((u >> 16) & 1);  // round-to-nearest-even
  return (ushort)(u >> 16);
}

// ---------------- degree count per (dst, etype) segment ----------------
__global__ void count_kernel(const int* __restrict__ ei, const int* __restrict__ et,
                             int* __restrict__ cnt, int E) {
  int e = blockIdx.x * blockDim.x + threadIdx.x;
  if (e < E) atomicAdd(&cnt[ei[E + e] * R_ET + et[e]], 1);
}

// ---------------- 3-phase exclusive scan over M = N*R segment counts ----------------
__global__ __launch_bounds__(1024) void scan1_kernel(const int* __restrict__ cnt,
                                                     int* __restrict__ off,
                                                     int* __restrict__ bsum, int M) {
  __shared__ int s[1024];
  int tid = threadIdx.x;
  int i = blockIdx.x * 1024 + tid;
  int d = (i < M) ? cnt[i] : 0;
  s[tid] = d;
  __syncthreads();
  for (int step = 1; step < 1024; step <<= 1) {
    int v = (tid >= step) ? s[tid - step] : 0;
    __syncthreads();
    s[tid] += v;
    __syncthreads();
  }
  if (i < M) off[i] = s[tid] - d;
  if (tid == 1023) bsum[blockIdx.x] = s[1023];
}

__global__ __launch_bounds__(1024) void scan2_kernel(int* __restrict__ bsum, int nb) {
  __shared__ int s[1024];
  int tid = threadIdx.x;
  int v = (tid < nb) ? bsum[tid] : 0;
  s[tid] = v;
  __syncthreads();
  for (int step = 1; step < 1024; step <<= 1) {
    int x = (tid >= step) ? s[tid - step] : 0;
    __syncthreads();
    s[tid] += x;
    __syncthreads();
  }
  if (tid < nb) bsum[tid] = s[tid] - v;
}

__global__ __launch_bounds__(1024) void scan3_kernel(int* __restrict__ off,
                                                     int* __restrict__ cursor,
                                                     const int* __restrict__ bsum,
                                                     int M, int E) {
  int i = blockIdx.x * 1024 + threadIdx.x;
  if (i < M) {
    int o = off[i] + bsum[blockIdx.x];
    off[i] = o;
    cursor[i] = o;
  }
  if (i == 0) off[M] = E;
}

// ---------------- place edges into (dst,r)-sorted slots (4B meta) ----------------
__global__ void place_kernel(const int* __restrict__ ei, const int* __restrict__ et,
                             int* __restrict__ cursor, int* __restrict__ meta, int E) {
  int e = blockIdx.x * blockDim.x + threadIdx.x;
  if (e >= E) return;
  int src = ei[e], dst = ei[E + e], r = et[e];
  int slot = atomicAdd(&cursor[dst * R_ET + r], 1);
  meta[slot] = src | (r << 28);  // src < 2^28, r < 8
}

// ---------------- weight convert+transpose: Wt[mat][n][k] bf16, swizzled ----------------
// mats 0..7 = W[r] (slab r), mat 8 = root (slab 8).
__global__ __launch_bounds__(256) void wconv_kernel(const float* __restrict__ root,
                                                    const float* __restrict__ W,
                                                    ushort* __restrict__ Wt) {
  int mat = blockIdx.x;
  const float* src = (mat == 8) ? root : (W + (size_t)mat * DH * DH);
  ushort* dst = Wt + (size_t)mat * DH * DH;
  for (int idx = threadIdx.x; idx < DH * DH; idx += 256) {
    int n = idx >> 7, k = idx & 127;
    dst[n * DH + (((k >> 3) ^ (n & 7)) << 3) + (k & 7)] = f2bf(src[k * DH + n]);
  }
}

// ---------------- activation convert (layer 0), zero-pads rows, swizzled ----------------
__global__ __launch_bounds__(256) void aconv_kernel(const float* __restrict__ src,
                                                    ushort* __restrict__ dst,
                                                    int total, int padtotal) {
  int i4 = (blockIdx.x * 256 + threadIdx.x) * 4;
  if (i4 >= padtotal) return;
  int row = i4 >> 7, k = i4 & 127;
  ushort4 o = make_ushort4(0, 0, 0, 0);
  if (i4 < total) {
    float4 v = *(const float4*)&src[i4];
    o = make_ushort4(f2bf(v.x), f2bf(v.y), f2bf(v.z), f2bf(v.w));
  }
  *(ushort4*)&dst[(size_t)row * DH + (((k >> 3) ^ (row & 7)) << 3) + (k & 7)] = o;
}

// ---------------- bf16 MFMA GEMM, 3 matrices per block, all-bf16 slabs ----------------
// grid (Npad/128, 3); mats = blockIdx.y*3 + m (0..8); t[mat] row-major [Npad][128] bf16.
__global__ __launch_bounds__(256) void gemm_mfma(
    const ushort* __restrict__ Abf, const ushort* __restrict__ Wt,
    ushort* __restrict__ t, int Npad) {
  __shared__ ushort As[128 * DH];  // 32 KB swizzled A-tile (persistent across mats)
  __shared__ ushort Bs[128 * DH];  // 32 KB swizzled B; reused as C-staging per mat
  const int tid = threadIdx.x;
  const int wave = tid >> 6, lane = tid & 63;
  const int quad = lane >> 4, l15 = lane & 15;
  const int rbase = blockIdx.x * 128;
  const int wr = (wave >> 1) * 64, wc = (wave & 1) * 64;

  const ushort* gA = Abf + (size_t)rbase * DH;
#pragma unroll
  for (int it = 0; it < 8; it++) {
    __builtin_amdgcn_global_load_lds(
        (const __attribute__((address_space(1))) void*)(gA + (it * 256 + tid) * 8),
        (__attribute__((address_space(3))) void*)(As + (it * 256 + wave * 64) * 8), 16, 0, 0);
  }

  for (int m = 0; m < 3; m++) {
    const int mat = blockIdx.y * 3 + m;
    const ushort* gB = Wt + (size_t)mat * DH * DH;
    if (m) __syncthreads();  // prior C-readout of Bs done
#pragma unroll
    for (int it = 0; it < 8; it++) {
      __builtin_amdgcn_global_load_lds(
          (const __attribute__((address_space(1))) void*)(gB + (it * 256 + tid) * 8),
          (__attribute__((address_space(3))) void*)(Bs + (it * 256 + wave * 64) * 8), 16, 0, 0);
    }
    __syncthreads();  // A (first iter) + B staged

    f32x4 acc[4][4];
#pragma unroll
    for (int i = 0; i < 4; i++)
#pragma unroll
      for (int j = 0; j < 4; j++) acc[i][j] = (f32x4){0.f, 0.f, 0.f, 0.f};

#pragma unroll
    for (int kc = 0; kc < 4; kc++) {
      bf16x8 af[4], bfr[4];
#pragma unroll
      for (int i = 0; i < 4; i++) {
        int ra = wr + i * 16 + l15;
        int rb = wc + i * 16 + l15;
        af[i] = *(const bf16x8*)&As[ra * DH + (((kc * 4 + quad) ^ (ra & 7)) << 3)];
        bfr[i] = *(const bf16x8*)&Bs[rb * DH + (((kc * 4 + quad) ^ (rb & 7)) << 3)];
      }
#pragma unroll
      for (int i = 0; i < 4; i++)
#pragma unroll
        for (int j = 0; j < 4; j++)
          acc[i][j] = __builtin_amdgcn_mfma_f32_16x16x32_bf16(af[i], bfr[j], acc[i][j], 0, 0, 0);
    }

    __syncthreads();  // all frag reads of Bs done -> reuse as C staging
#pragma unroll
    for (int i = 0; i < 4; i++)
#pragma unroll
      for (int j = 0; j < 4; j++) {
        int col = wc + j * 16 + l15;
#pragma unroll
        for (int r = 0; r < 4; r++)
          Bs[(wr + i * 16 + quad * 4 + r) * DH + col] = f2bf(acc[i][j][r]);
      }
    __syncthreads();
    ushort* tp = t + ((size_t)mat * Npad + rbase) * DH;
#pragma unroll
    for (int c = 0; c < 8; c++) {
      u16x8 v = *(const u16x8*)&Bs[tid * 64 + c * 8];
      *(u16x8*)&tp[tid * 64 + c * 8] = v;
    }
  }
}

// ---------------- gather core: (dst,r)-sorted meta; scale via shfl ----------------
__device__ __forceinline__ void gather_accum(const int* __restrict__ meta,
                                             const ushort* __restrict__ t,
                                             int start, int end, int lane, int colb,
                                             float invl, int NpadS,
                                             float& ax, float& ay) {
  for (int base = start; base < end; base += 64) {
    int m = min(64, end - base);
    int md = (lane < m) ? meta[base + lane] : 0;
    int j = 0;
    for (; j + 4 <= m; j += 4) {
      int p0 = __shfl(md, j), p1 = __shfl(md, j + 1);
      int p2 = __shfl(md, j + 2), p3 = __shfl(md, j + 3);
      int r0 = (unsigned)p0 >> 28, r1 = (unsigned)p1 >> 28;
      int r2 = (unsigned)p2 >> 28, r3 = (unsigned)p3 >> 28;
      float s0 = __shfl(invl, r0), s1 = __shfl(invl, r1);
      float s2 = __shfl(invl, r2), s3 = __shfl(invl, r3);
      unsigned u0 = *(const unsigned*)&t[r0 * NpadS + ((p0 & 0x0fffffff) << 7) + colb];
      unsigned u1 = *(const unsigned*)&t[r1 * NpadS + ((p1 & 0x0fffffff) << 7) + colb];
      unsigned u2 = *(const unsigned*)&t[r2 * NpadS + ((p2 & 0x0fffffff) << 7) + colb];
      unsigned u3 = *(const unsigned*)&t[r3 * NpadS + ((p3 & 0x0fffffff) << 7) + colb];
      ax = fmaf(__uint_as_float(u0 << 16), s0, ax);
      ay = fmaf(__uint_as_float(u0 & 0xffff0000u), s0, ay);
      ax = fmaf(__uint_as_float(u1 << 16), s1, ax);
      ay = fmaf(__uint_as_float(u1 & 0xffff0000u), s1, ay);
      ax = fmaf(__uint_as_float(u2 << 16), s2, ax);
      ay = fmaf(__uint_as_float(u2 & 0xffff0000u), s2, ay);
      ax = fmaf(__uint_as_float(u3 << 16), s3, ax);
      ay = fmaf(__uint_as_float(u3 & 0xffff0000u), s3, ay);
    }
    for (; j < m; j++) {
      int pj = __shfl(md, j);
      int rj = (unsigned)pj >> 28;
      float sj = __shfl(invl, rj);
      unsigned u = *(const unsigned*)&t[rj * NpadS + ((pj & 0x0fffffff) << 7) + colb];
      ax = fmaf(__uint_as_float(u << 16), sj, ax);
      ay = fmaf(__uint_as_float(u & 0xffff0000u), sj, ay);
    }
  }
}

// ---------------- gather (layers 0,1): Abf = bf16(relu(root + msgs + bias)) ----------
__global__ __launch_bounds__(256) void gather_mid(
    const int* __restrict__ off, const int* __restrict__ meta,
    const int* __restrict__ cnt, const ushort* __restrict__ t,
    const float* __restrict__ bias, ushort* __restrict__ Abf, int N, int Npad) {
  int dst = blockIdx.x * 4 + (threadIdx.x >> 6);
  if (dst >= N) return;
  int lane = threadIdx.x & 63, colb = lane * 2;
  int dst8 = dst * R_ET;
  int NpadS = Npad * DH;
  float invl = 1.f / (float)cnt[dst8 + (lane & 7)];  // inf if cnt==0 (never selected)
  float ax = 0.f, ay = 0.f;
  gather_accum(meta, t, off[dst8], off[dst8 + 8], lane, colb, invl, NpadS, ax, ay);
  unsigned u9 = *(const unsigned*)&t[8 * NpadS + (dst << 7) + colb];
  float2 bv = *(const float2*)&bias[colb];
  float rx = fmaxf(__uint_as_float(u9 << 16) + ax + bv.x, 0.f);
  float ry = fmaxf(__uint_as_float(u9 & 0xffff0000u) + ay + bv.y, 0.f);
  unsigned o = (unsigned)f2bf(rx) | ((unsigned)f2bf(ry) << 16);
  *(unsigned*)&Abf[(size_t)dst * DH + (((colb >> 3) ^ (dst & 7)) << 3) + (colb & 7)] = o;
}

// ---------------- gather (layer 2) + fused mean-pool column sums ----------------
// 4 dsts per wave; block-level reduce; 128 atomics/block. Bias added in MLP.
__global__ __launch_bounds__(256) void gather_last(
    const int* __restrict__ off, const int* __restrict__ meta,
    const int* __restrict__ cnt, const ushort* __restrict__ t,
    float* __restrict__ u, int N, int Npad) {
  __shared__ float sx[256], sy[256];
  int lane = threadIdx.x & 63, wave = threadIdx.x >> 6, colb = lane * 2;
  int NpadS = Npad * DH;
  float px = 0.f, py = 0.f;
  for (int dd = 0; dd < 4; dd++) {
    int dst = blockIdx.x * 16 + wave * 4 + dd;
    if (dst >= N) break;
    int dst8 = dst * R_ET;
    float invl = 1.f / (float)cnt[dst8 + (lane & 7)];
    float ax = 0.f, ay = 0.f;
    gather_accum(meta, t, off[dst8], off[dst8 + 8], lane, colb, invl, NpadS, ax, ay);
    unsigned u9 = *(const unsigned*)&t[8 * NpadS + (dst << 7) + colb];
    px += __uint_as_float(u9 << 16) + ax;
    py += __uint_as_float(u9 & 0xffff0000u) + ay;
  }
  sx[threadIdx.x] = px;
  sy[threadIdx.x] = py;
  __syncthreads();
  if (threadIdx.x < 64) {
    float tx = sx[threadIdx.x] + sx[64 + threadIdx.x] + sx[128 + threadIdx.x] + sx[192 + threadIdx.x];
    float ty = sy[threadIdx.x] + sy[64 + threadIdx.x] + sy[128 + threadIdx.x] + sy[192 + threadIdx.x];
    atomicAdd(&u[threadIdx.x * 2], tx);
    atomicAdd(&u[threadIdx.x * 2 + 1], ty);
  }
}

// ---------------- final MLP on concat(u1,u2)/N + bias2 ----------------
__global__ __launch_bounds__(256) void mlp_kernel(
    const float* __restrict__ u, const float* __restrict__ bias2,
    const float* __restrict__ fc1w, const float* __restrict__ fc1b,
    const float* __restrict__ fc2w, const float* __restrict__ fc2b,
    float* __restrict__ out, int N) {
  __shared__ float uin[256];
  __shared__ float hred[128];
  int tid = threadIdx.x;
  uin[tid] = u[tid] * (1.f / (float)N) + bias2[tid & 127];
  __syncthreads();
  if (tid < 128) {
    float s = fc1b[tid];
    for (int i = 0; i < 256; i++) s = fmaf(uin[i], fc1w[i * 128 + tid], s);
    s = fmaxf(s, 0.f);
    hred[tid] = s * fc2w[tid];
  }
  __syncthreads();
  if (tid == 0) {
    float s = fc2b[0];
    for (int i = 0; i < 128; i++) s += hred[i];
    out[0] = s;
  }
}

extern "C" void kernel_launch(void* const* d_in, const int* in_sizes, int n_in,
                              void* d_out, int out_size, void* d_ws, size_t ws_size,
                              hipStream_t stream) {
  const float* x[2] = {(const float*)d_in[0], (const float*)d_in[3]};
  const int* ei[2] = {(const int*)d_in[1], (const int*)d_in[4]};
  const int* et[2] = {(const int*)d_in[2], (const int*)d_in[5]};
  const float* Wp[3] = {(const float*)d_in[6], (const float*)d_in[9], (const float*)d_in[12]};
  const float* rootp[3] = {(const float*)d_in[7], (const float*)d_in[10], (const float*)d_in[13]};
  const float* biasp[3] = {(const float*)d_in[8], (const float*)d_in[11], (const float*)d_in[14]};
  const float* fc1w = (const float*)d_in[15];
  const float* fc1b = (const float*)d_in[16];
  const float* fc2w = (const float*)d_in[17];
  const float* fc2b = (const float*)d_in[18];

  const int N = in_sizes[0] / DH;
  const int E = in_sizes[2];
  const int Npad = (N + 127) & ~127;
  const int M = N * R_ET;
  const int MB = (M + 1023) / 1024;  // <= 1024

  char* ws = (char*)d_ws;
  size_t ob = 0;
  auto alloc = [&](size_t bytes) {
    void* p = ws + ob;
    ob = (ob + bytes + 255) & ~(size_t)255;
    return p;
  };
  int* cnt = (int*)alloc((size_t)M * 4);
  int* offs = (int*)alloc((size_t)(M + 1) * 4);
  int* cursor = (int*)alloc((size_t)M * 4);
  int* bsum = (int*)alloc(1024 * 4);
  int* meta = (int*)alloc((size_t)E * 4);
  float* u = (float*)alloc(1024);
  ushort* Abf = (ushort*)alloc((size_t)Npad * DH * 2);
  ushort* Wt = (ushort*)alloc((size_t)3 * 9 * DH * DH * 2);
  ushort* tbuf = (ushort*)alloc((size_t)9 * Npad * DH * 2);
  (void)ws_size;

  hipMemsetAsync(u, 0, 2 * DH * sizeof(float), stream);
  for (int l = 0; l < 3; l++)
    wconv_kernel<<<9, 256, 0, stream>>>(rootp[l], Wp[l], Wt + (size_t)l * 9 * DH * DH);

  dim3 ggrid(Npad / 128, 3);
  dim3 egrid((E + 255) / 256);
  const int total = N * DH, padtotal = Npad * DH;
  dim3 agrid((padtotal / 4 + 255) / 256);

  for (int g = 0; g < 2; g++) {
    hipMemsetAsync(cnt, 0, (size_t)M * sizeof(int), stream);
    count_kernel<<<egrid, 256, 0, stream>>>(ei[g], et[g], cnt, E);
    scan1_kernel<<<MB, 1024, 0, stream>>>(cnt, offs, bsum, M);
    scan2_kernel<<<1, 1024, 0, stream>>>(bsum, MB);
    scan3_kernel<<<MB, 1024, 0, stream>>>(offs, cursor, bsum, M, E);
    place_kernel<<<egrid, 256, 0, stream>>>(ei[g], et[g], cursor, meta, E);
    aconv_kernel<<<agrid, 256, 0, stream>>>(x[g], Abf, total, padtotal);
    for (int l = 0; l < 3; l++) {
      gemm_mfma<<<ggrid, 256, 0, stream>>>(Abf, Wt + (size_t)l * 9 * DH * DH, tbuf, Npad);
      if (l < 2) {
        gather_mid<<<(N + 3) / 4, 256, 0, stream>>>(offs, meta, cnt, tbuf, biasp[l],
                                                    Abf, N, Npad);
      } else {
        gather_last<<<(N + 15) / 16, 256, 0, stream>>>(offs, meta, cnt, tbuf,
                                                       u + g * DH, N, Npad);
      }
    }
  }
  mlp_kernel<<<1, 256, 0, stream>>>(u, biasp[2], fc1w, fc1b, fc2w, fc2b,
                                    (float*)d_out, N);
}

// Round 8
// 896.480 us; speedup vs baseline: 1.3228x; 1.3228x over previous
//
#include <hip/hip_runtime.h>

#define R_ET 8
#define DH 128

typedef __bf16 bf16x8 __attribute__((ext_vector_type(8)));
typedef float f32x4 __attribute__((ext_vector_type(4)));
typedef ushort u16x8 __attribute__((ext_vector_type(8)));

__device__ __forceinline__ ushort f2bf(float f) {
  unsigned u = __float_as_uint(f);
  u += 0x7fff + ((u >> 16) & 1);  // round-to-nearest-even
  return (ushort)(u >> 16);
}

// ---------------- degree count per (dst, etype) segment ----------------
__global__ void count_kernel(const int* __restrict__ ei, const int* __restrict__ et,
                             int* __restrict__ cnt, int E) {
  int e = blockIdx.x * blockDim.x + threadIdx.x;
  if (e < E) atomicAdd(&cnt[ei[E + e] * R_ET + et[e]], 1);
}

// ---------------- 3-phase exclusive scan over M = N*R segment counts ----------------
__global__ __launch_bounds__(1024) void scan1_kernel(const int* __restrict__ cnt,
                                                     int* __restrict__ off,
                                                     int* __restrict__ bsum, int M) {
  __shared__ int s[1024];
  int tid = threadIdx.x;
  int i = blockIdx.x * 1024 + tid;
  int d = (i < M) ? cnt[i] : 0;
  s[tid] = d;
  __syncthreads();
  for (int step = 1; step < 1024; step <<= 1) {
    int v = (tid >= step) ? s[tid - step] : 0;
    __syncthreads();
    s[tid] += v;
    __syncthreads();
  }
  if (i < M) off[i] = s[tid] - d;
  if (tid == 1023) bsum[blockIdx.x] = s[1023];
}

__global__ __launch_bounds__(1024) void scan2_kernel(int* __restrict__ bsum, int nb) {
  __shared__ int s[1024];
  int tid = threadIdx.x;
  int v = (tid < nb) ? bsum[tid] : 0;
  s[tid] = v;
  __syncthreads();
  for (int step = 1; step < 1024; step <<= 1) {
    int x = (tid >= step) ? s[tid - step] : 0;
    __syncthreads();
    s[tid] += x;
    __syncthreads();
  }
  if (tid < nb) bsum[tid] = s[tid] - v;
}

__global__ __launch_bounds__(1024) void scan3_kernel(int* __restrict__ off,
                                                     int* __restrict__ cursor,
                                                     const int* __restrict__ bsum,
                                                     int M, int E) {
  int i = blockIdx.x * 1024 + threadIdx.x;
  if (i < M) {
    int o = off[i] + bsum[blockIdx.x];
    off[i] = o;
    cursor[i] = o;
  }
  if (i == 0) off[M] = E;
}

// ---------------- place edges into (dst,r)-sorted slots (4B meta) ----------------
__global__ void place_kernel(const int* __restrict__ ei, const int* __restrict__ et,
                             int* __restrict__ cursor, int* __restrict__ meta, int E) {
  int e = blockIdx.x * blockDim.x + threadIdx.x;
  if (e >= E) return;
  int src = ei[e], dst = ei[E + e], r = et[e];
  int slot = atomicAdd(&cursor[dst * R_ET + r], 1);
  meta[slot] = src | (r << 28);  // src < 2^28, r < 8
}

// ---------------- weight convert+transpose: Wt[mat][n][k] bf16, swizzled ----------------
// mats 0..7 = W[r] (slab r), mat 8 = root (slab 8).
__global__ __launch_bounds__(256) void wconv_kernel(const float* __restrict__ root,
                                                    const float* __restrict__ W,
                                                    ushort* __restrict__ Wt) {
  int mat = blockIdx.x;
  const float* src = (mat == 8) ? root : (W + (size_t)mat * DH * DH);
  ushort* dst = Wt + (size_t)mat * DH * DH;
  for (int idx = threadIdx.x; idx < DH * DH; idx += 256) {
    int n = idx >> 7, k = idx & 127;
    dst[n * DH + (((k >> 3) ^ (n & 7)) << 3) + (k & 7)] = f2bf(src[k * DH + n]);
  }
}

// ---------------- activation convert (layer 0), zero-pads rows, swizzled ----------------
__global__ __launch_bounds__(256) void aconv_kernel(const float* __restrict__ src,
                                                    ushort* __restrict__ dst,
                                                    int total, int padtotal) {
  int i4 = (blockIdx.x * 256 + threadIdx.x) * 4;
  if (i4 >= padtotal) return;
  int row = i4 >> 7, k = i4 & 127;
  ushort4 o = make_ushort4(0, 0, 0, 0);
  if (i4 < total) {
    float4 v = *(const float4*)&src[i4];
    o = make_ushort4(f2bf(v.x), f2bf(v.y), f2bf(v.z), f2bf(v.w));
  }
  *(ushort4*)&dst[(size_t)row * DH + (((k >> 3) ^ (row & 7)) << 3) + (k & 7)] = o;
}

// ---------------- bf16 MFMA GEMM, 3 matrices per block, all-bf16 slabs ----------------
// grid (Npad/128, 3); mats = blockIdx.y*3 + m (0..8); t[mat] row-major [Npad][128] bf16.
__global__ __launch_bounds__(256) void gemm_mfma(
    const ushort* __restrict__ Abf, const ushort* __restrict__ Wt,
    ushort* __restrict__ t, int Npad) {
  __shared__ ushort As[128 * DH];  // 32 KB swizzled A-tile (persistent across mats)
  __shared__ ushort Bs[128 * DH];  // 32 KB swizzled B; reused as C-staging per mat
  const int tid = threadIdx.x;
  const int wave = tid >> 6, lane = tid & 63;
  const int quad = lane >> 4, l15 = lane & 15;
  const int rbase = blockIdx.x * 128;
  const int wr = (wave >> 1) * 64, wc = (wave & 1) * 64;

  const ushort* gA = Abf + (size_t)rbase * DH;
#pragma unroll
  for (int it = 0; it < 8; it++) {
    __builtin_amdgcn_global_load_lds(
        (const __attribute__((address_space(1))) void*)(gA + (it * 256 + tid) * 8),
        (__attribute__((address_space(3))) void*)(As + (it * 256 + wave * 64) * 8), 16, 0, 0);
  }

  for (int m = 0; m < 3; m++) {
    const int mat = blockIdx.y * 3 + m;
    const ushort* gB = Wt + (size_t)mat * DH * DH;
    if (m) __syncthreads();  // prior C-readout of Bs done
#pragma unroll
    for (int it = 0; it < 8; it++) {
      __builtin_amdgcn_global_load_lds(
          (const __attribute__((address_space(1))) void*)(gB + (it * 256 + tid) * 8),
          (__attribute__((address_space(3))) void*)(Bs + (it * 256 + wave * 64) * 8), 16, 0, 0);
    }
    __syncthreads();  // A (first iter) + B staged

    f32x4 acc[4][4];
#pragma unroll
    for (int i = 0; i < 4; i++)
#pragma unroll
      for (int j = 0; j < 4; j++) acc[i][j] = (f32x4){0.f, 0.f, 0.f, 0.f};

#pragma unroll
    for (int kc = 0; kc < 4; kc++) {
      bf16x8 af[4], bfr[4];
#pragma unroll
      for (int i = 0; i < 4; i++) {
        int ra = wr + i * 16 + l15;
        int rb = wc + i * 16 + l15;
        af[i] = *(const bf16x8*)&As[ra * DH + (((kc * 4 + quad) ^ (ra & 7)) << 3)];
        bfr[i] = *(const bf16x8*)&Bs[rb * DH + (((kc * 4 + quad) ^ (rb & 7)) << 3)];
      }
#pragma unroll
      for (int i = 0; i < 4; i++)
#pragma unroll
        for (int j = 0; j < 4; j++)
          acc[i][j] = __builtin_amdgcn_mfma_f32_16x16x32_bf16(af[i], bfr[j], acc[i][j], 0, 0, 0);
    }

    __syncthreads();  // all frag reads of Bs done -> reuse as C staging
#pragma unroll
    for (int i = 0; i < 4; i++)
#pragma unroll
      for (int j = 0; j < 4; j++) {
        int col = wc + j * 16 + l15;
#pragma unroll
        for (int r = 0; r < 4; r++)
          Bs[(wr + i * 16 + quad * 4 + r) * DH + col] = f2bf(acc[i][j][r]);
      }
    __syncthreads();
    ushort* tp = t + ((size_t)mat * Npad + rbase) * DH;
#pragma unroll
    for (int c = 0; c < 8; c++) {
      u16x8 v = *(const u16x8*)&Bs[tid * 64 + c * 8];
      *(u16x8*)&tp[tid * 64 + c * 8] = v;
    }
  }
}

// ---------------- gather core: (dst,r)-sorted meta; scale via shfl ----------------
__device__ __forceinline__ void gather_accum(const int* __restrict__ meta,
                                             const ushort* __restrict__ t,
                                             int start, int end, int lane, int colb,
                                             float invl, int NpadS,
                                             float& ax, float& ay) {
  for (int base = start; base < end; base += 64) {
    int m = min(64, end - base);
    int md = (lane < m) ? meta[base + lane] : 0;
    int j = 0;
    for (; j + 4 <= m; j += 4) {
      int p0 = __shfl(md, j), p1 = __shfl(md, j + 1);
      int p2 = __shfl(md, j + 2), p3 = __shfl(md, j + 3);
      int r0 = (unsigned)p0 >> 28, r1 = (unsigned)p1 >> 28;
      int r2 = (unsigned)p2 >> 28, r3 = (unsigned)p3 >> 28;
      float s0 = __shfl(invl, r0), s1 = __shfl(invl, r1);
      float s2 = __shfl(invl, r2), s3 = __shfl(invl, r3);
      unsigned u0 = *(const unsigned*)&t[r0 * NpadS + ((p0 & 0x0fffffff) << 7) + colb];
      unsigned u1 = *(const unsigned*)&t[r1 * NpadS + ((p1 & 0x0fffffff) << 7) + colb];
      unsigned u2 = *(const unsigned*)&t[r2 * NpadS + ((p2 & 0x0fffffff) << 7) + colb];
      unsigned u3 = *(const unsigned*)&t[r3 * NpadS + ((p3 & 0x0fffffff) << 7) + colb];
      ax = fmaf(__uint_as_float(u0 << 16), s0, ax);
      ay = fmaf(__uint_as_float(u0 & 0xffff0000u), s0, ay);
      ax = fmaf(__uint_as_float(u1 << 16), s1, ax);
      ay = fmaf(__uint_as_float(u1 & 0xffff0000u), s1, ay);
      ax = fmaf(__uint_as_float(u2 << 16), s2, ax);
      ay = fmaf(__uint_as_float(u2 & 0xffff0000u), s2, ay);
      ax = fmaf(__uint_as_float(u3 << 16), s3, ax);
      ay = fmaf(__uint_as_float(u3 & 0xffff0000u), s3, ay);
    }
    for (; j < m; j++) {
      int pj = __shfl(md, j);
      int rj = (unsigned)pj >> 28;
      float sj = __shfl(invl, rj);
      unsigned u = *(const unsigned*)&t[rj * NpadS + ((pj & 0x0fffffff) << 7) + colb];
      ax = fmaf(__uint_as_float(u << 16), sj, ax);
      ay = fmaf(__uint_as_float(u & 0xffff0000u), sj, ay);
    }
  }
}

// ---------------- gather (layers 0,1): Abf = bf16(relu(root + msgs + bias)) ----------
__global__ __launch_bounds__(256) void gather_mid(
    const int* __restrict__ off, const int* __restrict__ meta,
    const int* __restrict__ cnt, const ushort* __restrict__ t,
    const float* __restrict__ bias, ushort* __restrict__ Abf, int N, int Npad) {
  int dst = blockIdx.x * 4 + (threadIdx.x >> 6);
  if (dst >= N) return;
  int lane = threadIdx.x & 63, colb = lane * 2;
  int dst8 = dst * R_ET;
  int NpadS = Npad * DH;
  float invl = 1.f / (float)cnt[dst8 + (lane & 7)];  // inf if cnt==0 (never selected)
  float ax = 0.f, ay = 0.f;
  gather_accum(meta, t, off[dst8], off[dst8 + 8], lane, colb, invl, NpadS, ax, ay);
  unsigned u9 = *(const unsigned*)&t[8 * NpadS + (dst << 7) + colb];
  float2 bv = *(const float2*)&bias[colb];
  float rx = fmaxf(__uint_as_float(u9 << 16) + ax + bv.x, 0.f);
  float ry = fmaxf(__uint_as_float(u9 & 0xffff0000u) + ay + bv.y, 0.f);
  unsigned o = (unsigned)f2bf(rx) | ((unsigned)f2bf(ry) << 16);
  *(unsigned*)&Abf[(size_t)dst * DH + (((colb >> 3) ^ (dst & 7)) << 3) + (colb & 7)] = o;
}

// ---------------- gather (layer 2) + fused mean-pool, 1 dst/wave ----------------
// Block-level reduce across 4 waves, then spread atomics over 64 partial buffers
// (each of the 128 column addresses sees ~N/4/64 ~ 195 adds, no serialization).
__global__ __launch_bounds__(256) void gather_last(
    const int* __restrict__ off, const int* __restrict__ meta,
    const int* __restrict__ cnt, const ushort* __restrict__ t,
    float* __restrict__ upart, int N, int Npad) {
  __shared__ float sx[256], sy[256];
  int dst = blockIdx.x * 4 + (threadIdx.x >> 6);
  int lane = threadIdx.x & 63, colb = lane * 2;
  float px = 0.f, py = 0.f;
  if (dst < N) {
    int dst8 = dst * R_ET;
    int NpadS = Npad * DH;
    float invl = 1.f / (float)cnt[dst8 + (lane & 7)];
    float ax = 0.f, ay = 0.f;
    gather_accum(meta, t, off[dst8], off[dst8 + 8], lane, colb, invl, NpadS, ax, ay);
    unsigned u9 = *(const unsigned*)&t[8 * NpadS + (dst << 7) + colb];
    px = __uint_as_float(u9 << 16) + ax;
    py = __uint_as_float(u9 & 0xffff0000u) + ay;
  }
  sx[threadIdx.x] = px;
  sy[threadIdx.x] = py;
  __syncthreads();
  if (threadIdx.x < 64) {
    float tx = sx[threadIdx.x] + sx[64 + threadIdx.x] + sx[128 + threadIdx.x] + sx[192 + threadIdx.x];
    float ty = sy[threadIdx.x] + sy[64 + threadIdx.x] + sy[128 + threadIdx.x] + sy[192 + threadIdx.x];
    float* up = upart + (size_t)(blockIdx.x & 63) * DH;
    atomicAdd(&up[threadIdx.x * 2], tx);
    atomicAdd(&up[threadIdx.x * 2 + 1], ty);
  }
}

// ---------------- final MLP: reduce 64 partials, /N, +bias2, 2-layer MLP ----------
__global__ __launch_bounds__(256) void mlp_kernel(
    const float* __restrict__ upart, const float* __restrict__ bias2,
    const float* __restrict__ fc1w, const float* __restrict__ fc1b,
    const float* __restrict__ fc2w, const float* __restrict__ fc2b,
    float* __restrict__ out, int N) {
  __shared__ float uin[256];
  __shared__ float hred[128];
  int tid = threadIdx.x;
  {
    int g = tid >> 7, col = tid & 127;
    const float* up = upart + (size_t)g * 64 * DH + col;
    float s = 0.f;
#pragma unroll
    for (int p = 0; p < 64; p++) s += up[(size_t)p * DH];
    uin[tid] = s * (1.f / (float)N) + bias2[col];
  }
  __syncthreads();
  if (tid < 128) {
    float s = fc1b[tid];
    for (int i = 0; i < 256; i++) s = fmaf(uin[i], fc1w[i * 128 + tid], s);
    s = fmaxf(s, 0.f);
    hred[tid] = s * fc2w[tid];
  }
  __syncthreads();
  if (tid == 0) {
    float s = fc2b[0];
    for (int i = 0; i < 128; i++) s += hred[i];
    out[0] = s;
  }
}

extern "C" void kernel_launch(void* const* d_in, const int* in_sizes, int n_in,
                              void* d_out, int out_size, void* d_ws, size_t ws_size,
                              hipStream_t stream) {
  const float* x[2] = {(const float*)d_in[0], (const float*)d_in[3]};
  const int* ei[2] = {(const int*)d_in[1], (const int*)d_in[4]};
  const int* et[2] = {(const int*)d_in[2], (const int*)d_in[5]};
  const float* Wp[3] = {(const float*)d_in[6], (const float*)d_in[9], (const float*)d_in[12]};
  const float* rootp[3] = {(const float*)d_in[7], (const float*)d_in[10], (const float*)d_in[13]};
  const float* biasp[3] = {(const float*)d_in[8], (const float*)d_in[11], (const float*)d_in[14]};
  const float* fc1w = (const float*)d_in[15];
  const float* fc1b = (const float*)d_in[16];
  const float* fc2w = (const float*)d_in[17];
  const float* fc2b = (const float*)d_in[18];

  const int N = in_sizes[0] / DH;
  const int E = in_sizes[2];
  const int Npad = (N + 127) & ~127;
  const int M = N * R_ET;
  const int MB = (M + 1023) / 1024;  // <= 1024

  char* ws = (char*)d_ws;
  size_t ob = 0;
  auto alloc = [&](size_t bytes) {
    void* p = ws + ob;
    ob = (ob + bytes + 255) & ~(size_t)255;
    return p;
  };
  int* cnt = (int*)alloc((size_t)M * 4);
  int* offs = (int*)alloc((size_t)(M + 1) * 4);
  int* cursor = (int*)alloc((size_t)M * 4);
  int* bsum = (int*)alloc(1024 * 4);
  int* meta = (int*)alloc((size_t)E * 4);
  float* upart = (float*)alloc((size_t)2 * 64 * DH * 4);  // [graph][64][128]
  ushort* Abf = (ushort*)alloc((size_t)Npad * DH * 2);
  ushort* Wt = (ushort*)alloc((size_t)3 * 9 * DH * DH * 2);
  ushort* tbuf = (ushort*)alloc((size_t)9 * Npad * DH * 2);
  (void)ws_size;

  hipMemsetAsync(upart, 0, (size_t)2 * 64 * DH * sizeof(float), stream);
  for (int l = 0; l < 3; l++)
    wconv_kernel<<<9, 256, 0, stream>>>(rootp[l], Wp[l], Wt + (size_t)l * 9 * DH * DH);

  dim3 ggrid(Npad / 128, 3);
  dim3 egrid((E + 255) / 256);
  const int total = N * DH, padtotal = Npad * DH;
  dim3 agrid((padtotal / 4 + 255) / 256);

  for (int g = 0; g < 2; g++) {
    hipMemsetAsync(cnt, 0, (size_t)M * sizeof(int), stream);
    count_kernel<<<egrid, 256, 0, stream>>>(ei[g], et[g], cnt, E);
    scan1_kernel<<<MB, 1024, 0, stream>>>(cnt, offs, bsum, M);
    scan2_kernel<<<1, 1024, 0, stream>>>(bsum, MB);
    scan3_kernel<<<MB, 1024, 0, stream>>>(offs, cursor, bsum, M, E);
    place_kernel<<<egrid, 256, 0, stream>>>(ei[g], et[g], cursor, meta, E);
    aconv_kernel<<<agrid, 256, 0, stream>>>(x[g], Abf, total, padtotal);
    for (int l = 0; l < 3; l++) {
      gemm_mfma<<<ggrid, 256, 0, stream>>>(Abf, Wt + (size_t)l * 9 * DH * DH, tbuf, Npad);
      if (l < 2) {
        gather_mid<<<(N + 3) / 4, 256, 0, stream>>>(offs, meta, cnt, tbuf, biasp[l],
                                                    Abf, N, Npad);
      } else {
        gather_last<<<(N + 3) / 4, 256, 0, stream>>>(offs, meta, cnt, tbuf,
                                                     upart + (size_t)g * 64 * DH, N, Npad);
      }
    }
  }
  mlp_kernel<<<1, 256, 0, stream>>>(upart, biasp[2], fc1w, fc1b, fc2w, fc2b,
                                    (float*)d_out, N);
}